// Round 5
// baseline (431.866 us; speedup 1.0000x reference)
//
#include <hip/hip_runtime.h>

#define N_NODES 100000
#define E_EDGES 600000
#define LATDIM 128
#define HEAD 4
#define HDIM 32

#define SCAN_CHUNK 1024
#define SCAN_NB ((N_NODES + SCAN_CHUNK - 1) / SCAN_CHUNK)   // 98

__device__ __forceinline__ unsigned f32_to_bf16_rne(float x) {
    unsigned u = __float_as_uint(x);
    u += 0x7fffu + ((u >> 16) & 1u);   // round to nearest even
    return u >> 16;
}

// One GEMM pass over the staged 64x128 tile: acc[8][4] (+=) smem @ W.
// k processed in chunks of 4: 4 independent weight float4 loads +
// 8 ds_read_b128 + 128 FMAs per chunk.
__device__ __forceinline__ void gemm_pass(
    const float (*smem)[128], const float* __restrict__ W,
    int cg, int rg, float4 acc[8])
{
    const float4* Wf4 = (const float4*)W;
    for (int k4 = 0; k4 < 32; ++k4) {
        float4 w0 = Wf4[(k4 * 4 + 0) * 32 + cg];
        float4 w1 = Wf4[(k4 * 4 + 1) * 32 + cg];
        float4 w2 = Wf4[(k4 * 4 + 2) * 32 + cg];
        float4 w3 = Wf4[(k4 * 4 + 3) * 32 + cg];
        #pragma unroll
        for (int i = 0; i < 8; ++i) {
            float4 e = *((const float4*)&smem[rg * 8 + i][k4 * 4]);
            acc[i].x += e.x * w0.x + e.y * w1.x + e.z * w2.x + e.w * w3.x;
            acc[i].y += e.x * w0.y + e.y * w1.y + e.z * w2.y + e.w * w3.y;
            acc[i].z += e.x * w0.z + e.y * w1.z + e.z * w2.z + e.w * w3.z;
            acc[i].w += e.x * w0.w + e.y * w1.w + e.z * w2.w + e.w * w3.w;
        }
    }
}

// ---------------------------------------------------------------------------
// Kernel A: fused per-node Q/K/V transform.
//   Q written f32; K,V packed as bf16 pair into one uint per (node, dim).
// ---------------------------------------------------------------------------
__global__ __launch_bounds__(256) void qkv_kernel(
    const float* __restrict__ embeds,
    const float* __restrict__ qT,
    const float* __restrict__ kT,
    const float* __restrict__ vT,
    float* __restrict__ Q, unsigned* __restrict__ KV)
{
    __shared__ float smem[64][128];   // 32 KiB
    const int rowBase = blockIdx.x * 64;
    const int tid = threadIdx.x;

    for (int i = tid; i < 64 * 32; i += 256) {   // 2048 float4
        int r  = i >> 5;
        int c4 = i & 31;
        int gr = rowBase + r;
        float4 val = make_float4(0.f, 0.f, 0.f, 0.f);
        if (gr < N_NODES) val = ((const float4*)embeds)[gr * 32 + c4];
        ((float4*)&smem[r][0])[c4] = val;
    }
    __syncthreads();

    const int cg = tid & 31;      // col group (4 cols)
    const int rg = tid >> 5;      // row group (8 rows)

    float4 acc[8];
    float4 kacc[8];

    // ---- Q pass ----
    #pragma unroll
    for (int i = 0; i < 8; ++i) acc[i] = make_float4(0.f, 0.f, 0.f, 0.f);
    gemm_pass(smem, qT, cg, rg, acc);
    #pragma unroll
    for (int i = 0; i < 8; ++i) {
        int gr = rowBase + rg * 8 + i;
        if (gr < N_NODES)
            ((float4*)(Q + (size_t)gr * 128))[cg] = acc[i];
    }

    // ---- K pass (keep in kacc) ----
    #pragma unroll
    for (int i = 0; i < 8; ++i) kacc[i] = make_float4(0.f, 0.f, 0.f, 0.f);
    gemm_pass(smem, kT, cg, rg, kacc);

    // ---- V pass, then pack (k,v) -> uint ----
    #pragma unroll
    for (int i = 0; i < 8; ++i) acc[i] = make_float4(0.f, 0.f, 0.f, 0.f);
    gemm_pass(smem, vT, cg, rg, acc);

    #pragma unroll
    for (int i = 0; i < 8; ++i) {
        int gr = rowBase + rg * 8 + i;
        if (gr < N_NODES) {
            uint4 p;
            p.x = f32_to_bf16_rne(kacc[i].x) | (f32_to_bf16_rne(acc[i].x) << 16);
            p.y = f32_to_bf16_rne(kacc[i].y) | (f32_to_bf16_rne(acc[i].y) << 16);
            p.z = f32_to_bf16_rne(kacc[i].z) | (f32_to_bf16_rne(acc[i].z) << 16);
            p.w = f32_to_bf16_rne(kacc[i].w) | (f32_to_bf16_rne(acc[i].w) << 16);
            ((uint4*)(KV + (size_t)gr * 128))[cg] = p;
        }
    }
}

// ---------------------------------------------------------------------------
// CSR build: histogram -> exclusive scan -> scatter (stores COLS directly)
// ---------------------------------------------------------------------------
__global__ __launch_bounds__(256) void hist_kernel(
    const int* __restrict__ rows, int* __restrict__ counts)
{
    int e = blockIdx.x * 256 + threadIdx.x;
    if (e < E_EDGES) atomicAdd(&counts[rows[e]], 1);
}

__global__ __launch_bounds__(256) void scan1_kernel(
    const int* __restrict__ counts, int* __restrict__ starts,
    int* __restrict__ blockSums)
{
    __shared__ int s[256];
    int b = blockIdx.x, t = threadIdx.x;
    int base = b * SCAN_CHUNK + t * 4;
    int v0 = (base + 0 < N_NODES) ? counts[base + 0] : 0;
    int v1 = (base + 1 < N_NODES) ? counts[base + 1] : 0;
    int v2 = (base + 2 < N_NODES) ? counts[base + 2] : 0;
    int v3 = (base + 3 < N_NODES) ? counts[base + 3] : 0;
    int local = v0 + v1 + v2 + v3;
    s[t] = local;
    __syncthreads();
    for (int off = 1; off < 256; off <<= 1) {
        int x = (t >= off) ? s[t - off] : 0;
        __syncthreads();
        s[t] += x;
        __syncthreads();
    }
    int incl = s[t];
    int excl = incl - local;
    if (base + 0 < N_NODES) starts[base + 0] = excl;
    if (base + 1 < N_NODES) starts[base + 1] = excl + v0;
    if (base + 2 < N_NODES) starts[base + 2] = excl + v0 + v1;
    if (base + 3 < N_NODES) starts[base + 3] = excl + v0 + v1 + v2;
    if (t == 255) blockSums[b] = incl;
}

__global__ __launch_bounds__(128) void scan2_kernel(int* __restrict__ blockSums)
{
    __shared__ int s[128];
    int t = threadIdx.x;
    int v = (t < SCAN_NB) ? blockSums[t] : 0;
    s[t] = v;
    __syncthreads();
    for (int off = 1; off < 128; off <<= 1) {
        int x = (t >= off) ? s[t - off] : 0;
        __syncthreads();
        s[t] += x;
        __syncthreads();
    }
    if (t < SCAN_NB) blockSums[t] = s[t] - v;   // exclusive
}

__global__ __launch_bounds__(256) void scan3_kernel(
    int* __restrict__ starts, const int* __restrict__ blockSums,
    int* __restrict__ cursor)
{
    int i = blockIdx.x * 256 + threadIdx.x;
    if (i < N_NODES) {
        int v = starts[i] + blockSums[i >> 10];
        starts[i] = v;
        cursor[i] = v;
    }
}

__global__ __launch_bounds__(256) void scatter_kernel(
    const int* __restrict__ rows, const int* __restrict__ cols,
    int* __restrict__ cursor, int* __restrict__ csrCols)
{
    int e = blockIdx.x * 256 + threadIdx.x;
    if (e >= E_EDGES) return;
    int pos = atomicAdd(&cursor[rows[e]], 1);
    csrCols[pos] = cols[e];
}

// ---------------------------------------------------------------------------
// Kernel B: fused attention + aggregation, bf16-packed K/V, 2-edge unroll.
// ---------------------------------------------------------------------------
__global__ __launch_bounds__(256) void att_agg_kernel(
    const float* __restrict__ Q, const unsigned* __restrict__ KV,
    const float* __restrict__ filt,
    const int* __restrict__ starts, const int* __restrict__ counts,
    const int* __restrict__ csrCols,
    float* __restrict__ out)
{
    int t = threadIdx.x;
    int node = blockIdx.x * 2 + (t >> 7);
    if (node >= N_NODES) return;
    int d = t & 127;
    int h = d >> 5;

    float qd  = Q[(size_t)node * 128 + d];
    int   s   = starts[node];
    int   cnt = counts[node];

    float norm = 0.f, acc = 0.f;
    int i = 0;
    for (; i + 2 <= cnt; i += 2) {
        int c0 = csrCols[s + i];
        int c1 = csrCols[s + i + 1];
        unsigned kv0 = KV[(size_t)c0 * 128 + d];
        unsigned kv1 = KV[(size_t)c1 * 128 + d];
        float f0 = filt[(size_t)c0 * HEAD + h];
        float f1 = filt[(size_t)c1 * HEAD + h];
        float k0 = __uint_as_float(kv0 << 16);
        float v0 = __uint_as_float(kv0 & 0xffff0000u);
        float k1 = __uint_as_float(kv1 << 16);
        float v1 = __uint_as_float(kv1 & 0xffff0000u);

        float p0 = qd * k0;
        float p1 = qd * k1;
        p0 += __shfl_xor(p0, 1);   p1 += __shfl_xor(p1, 1);
        p0 += __shfl_xor(p0, 2);   p1 += __shfl_xor(p1, 2);
        p0 += __shfl_xor(p0, 4);   p1 += __shfl_xor(p1, 4);
        p0 += __shfl_xor(p0, 8);   p1 += __shfl_xor(p1, 8);
        p0 += __shfl_xor(p0, 16);  p1 += __shfl_xor(p1, 16);

        float w0 = __expf(fminf(fmaxf(p0, -10.f), 10.f) + f0);
        float w1 = __expf(fminf(fmaxf(p1, -10.f), 10.f) + f1);
        norm += w0 + w1;
        acc  += w0 * v0 + w1 * v1;
    }
    if (i < cnt) {
        int c0 = csrCols[s + i];
        unsigned kv0 = KV[(size_t)c0 * 128 + d];
        float f0 = filt[(size_t)c0 * HEAD + h];
        float k0 = __uint_as_float(kv0 << 16);
        float v0 = __uint_as_float(kv0 & 0xffff0000u);
        float p0 = qd * k0;
        p0 += __shfl_xor(p0, 1);
        p0 += __shfl_xor(p0, 2);
        p0 += __shfl_xor(p0, 4);
        p0 += __shfl_xor(p0, 8);
        p0 += __shfl_xor(p0, 16);
        float w0 = __expf(fminf(fmaxf(p0, -10.f), 10.f) + f0);
        norm += w0;
        acc  += w0 * v0;
    }
    out[(size_t)node * 128 + d] = acc / (norm + 1e-8f);
}

// ---------------------------------------------------------------------------
extern "C" void kernel_launch(void* const* d_in, const int* in_sizes, int n_in,
                              void* d_out, int out_size, void* d_ws, size_t ws_size,
                              hipStream_t stream) {
    const float* embeds = (const float*)d_in[0];
    const float* qT     = (const float*)d_in[1];
    const float* kT     = (const float*)d_in[2];
    const float* vT     = (const float*)d_in[3];
    const float* filt   = (const float*)d_in[4];
    const int*   rows   = (const int*)d_in[5];
    const int*   cols   = (const int*)d_in[6];
    float*       out    = (float*)d_out;

    // Workspace: Q: N*128 f32 | KV: N*128 u32 | counts,starts,cursor: N i32 |
    //            blockSums: 128 i32 | csrCols: E i32
    float*    Q  = (float*)d_ws;
    unsigned* KV = (unsigned*)(Q + (size_t)N_NODES * 128);
    int* counts    = (int*)(KV + (size_t)N_NODES * 128);
    int* starts    = counts + N_NODES;
    int* cursor    = starts + N_NODES;
    int* blockSums = cursor + N_NODES;
    int* csrCols   = blockSums + 128;

    hipMemsetAsync(counts, 0, sizeof(int) * N_NODES, stream);

    qkv_kernel<<<(N_NODES + 63) / 64, 256, 0, stream>>>(embeds, qT, kT, vT, Q, KV);

    hist_kernel<<<(E_EDGES + 255) / 256, 256, 0, stream>>>(rows, counts);
    scan1_kernel<<<SCAN_NB, 256, 0, stream>>>(counts, starts, blockSums);
    scan2_kernel<<<1, 128, 0, stream>>>(blockSums);
    scan3_kernel<<<(N_NODES + 255) / 256, 256, 0, stream>>>(starts, blockSums, cursor);
    scatter_kernel<<<(E_EDGES + 255) / 256, 256, 0, stream>>>(rows, cols, cursor, csrCols);

    att_agg_kernel<<<(N_NODES + 1) / 2, 256, 0, stream>>>(
        Q, KV, filt, starts, counts, csrCols, out);
}